// Round 9
// baseline (437.253 us; speedup 1.0000x reference)
//
#include <hip/hip_runtime.h>
#include <hip/hip_fp16.h>
#include <math.h>

#define NN 10000
#define NE 320000

typedef __attribute__((ext_vector_type(8))) short s8v;       // 8x16-bit (4 VGPRs)
typedef __attribute__((ext_vector_type(8))) _Float16 h8v;    // 8 f16 (4 VGPRs) MFMA frag
typedef __attribute__((ext_vector_type(4))) float f4v;       // MFMA accumulator

__device__ __forceinline__ short f2h(float f) {
  _Float16 h = (_Float16)f;            // v_cvt_f16_f32 (RNE)
  short s; __builtin_memcpy(&s, &h, 2); return s;
}
// relu(f16a + f16b) on a packed pair: v_pk_add_f16 + v_pk_max_f16 (2 VALU ops).
// TWO single-instruction asm statements, NOT one multi-inst block with "=&v":
// a single instruction reads all inputs before writing its dest, so no
// early-clobber is needed and the allocator may alias dest with inputs.
// (The round-6/7 multi-inst early-clobber version cost ~12 extra VGPRs ->
// pushed the (512,4) build into acc-spill / the (512,3) build to 1 block/CU.)
__device__ __forceinline__ unsigned cvt_pair(unsigned wa, unsigned wb) {
  unsigned r;
  asm("v_pk_add_f16 %0, %1, %2" : "=v"(r) : "v"(wa), "v"(wb));
  asm("v_pk_max_f16 %0, %1, 0" : "=v"(r) : "v"(r));
  return r;
}

// ================= edge sort by dst (counting sort) =================
__global__ void hist_kernel(const int* __restrict__ ei, int* __restrict__ cnt) {
  int e = blockIdx.x * 256 + threadIdx.x;
  if (e < NE) atomicAdd(&cnt[ei[NE + e]], 1);
}

__global__ void __launch_bounds__(1024)
scan_kernel(const int* __restrict__ cnt, int* __restrict__ cur) {
  __shared__ int part[1024];
  const int t = threadIdx.x;
  const int base = t * 10;
  int local[10];
  int s = 0;
#pragma unroll
  for (int u = 0; u < 10; ++u) {
    int c = (base + u < NN) ? cnt[base + u] : 0;
    local[u] = s; s += c;
  }
  part[t] = s;
  __syncthreads();
  for (int off = 1; off < 1024; off <<= 1) {
    int v = part[t];
    int w = (t >= off) ? part[t - off] : 0;
    __syncthreads();
    part[t] = v + w;
    __syncthreads();
  }
  int excl = (t == 0) ? 0 : part[t - 1];
#pragma unroll
  for (int u = 0; u < 10; ++u)
    if (base + u < NN) cur[base + u] = excl + local[u];
}

__global__ void scatter_kernel(const int* __restrict__ ei, int* __restrict__ cur,
                               int* __restrict__ sSrc, int* __restrict__ sDst) {
  int e = blockIdx.x * 256 + threadIdx.x;
  if (e < NE) {
    int d = ei[NE + e];
    int p = atomicAdd(&cur[d], 1);
    sSrc[p] = ei[e];
    sDst[p] = d;
  }
}

// ================= prep: combined/transposed weights, fp32 -> f16 =================
// Wp1T [1024][128], Wp2T [512][256] : node-GEMM layouts (row n, col k)
// BTf1 / BTf2 : edge-GEMM fragment layout: idx = (k>>5)*(NT*32) + n*32 + (k&31)
__global__ void prep_weights(const float* __restrict__ W1a, const float* __restrict__ W1b,
                             const float* __restrict__ W2a, const float* __restrict__ W2b,
                             short* __restrict__ Wp1T, short* __restrict__ Wp2T,
                             short* __restrict__ BTf1, short* __restrict__ BTf2) {
  int i = blockIdx.x * 256 + threadIdx.x;
  if (i < 131072) {                        // Wp1T[j][k], j<1024, k<128
    int j = i >> 7, k = i & 127;
    float v;
    if (j < 512) v = W1a[k * 512 + j] - W1a[(k + 128) * 512 + j];
    else         v = W1a[(k + 128) * 512 + (j - 512)];
    Wp1T[i] = f2h(v);
  } else if (i < 262144) {                 // Wp2T[j][k], j<512, k<256
    int t = i - 131072;
    int j = t >> 8, k = t & 255;
    float v;
    if (j < 256) v = W1b[k * 256 + j] - W1b[(k + 256) * 256 + j];
    else         v = W1b[(k + 256) * 256 + (j - 256)];
    Wp2T[t] = f2h(v);
  } else if (i < 393216) {                 // BTf1: W2a^T fragment layout (NT=256, K=512)
    int t = i - 262144;
    int n = t >> 9, k = t & 511;
    BTf1[(k >> 5) * 8192 + n * 32 + (k & 31)] = f2h(W2a[k * 256 + n]);
  } else if (i < 425984) {                 // BTf2: W2b^T fragment layout (NT=128, K=256)
    int t = i - 393216;
    int n = t >> 8, k = t & 255;
    BTf2[(k >> 5) * 4096 + n * 32 + (k & 31)] = f2h(W2b[k * 128 + n]);
  }
}

// ================= node GEMM: C[NN][Ntot](f16) = A[NN][K](fp32) @ BT^T + bias ===========
template<int K>
__global__ void __launch_bounds__(256)
node_gemm(const float* __restrict__ A, const short* __restrict__ BT,
          const float* __restrict__ bias, int biasLen,
          short* __restrict__ C, int Ntot) {
  const int rowBase = blockIdx.x * 64;
  const int wave = threadIdx.x >> 6, lane = threadIdx.x & 63;
  const int colBase = blockIdx.y * 256 + wave * 64;
  const int lm = lane & 15, q = lane >> 4;
  f4v acc[4][4] = {};
  int arow[4];
#pragma unroll
  for (int mt = 0; mt < 4; ++mt) {
    int r = rowBase + mt * 16 + lm;
    arow[mt] = r < NN ? r : NN - 1;        // clamp; stores guarded below
  }
  for (int kk = 0; kk < K; kk += 32) {
    const int k = kk + q * 8;
    h8v aF[4], bF[4];
#pragma unroll
    for (int mt = 0; mt < 4; ++mt) {
      const float4* ap = (const float4*)(A + (size_t)arow[mt] * K + k);
      float4 x0 = ap[0], x1 = ap[1];
      h8v t;
      t[0] = (_Float16)x0.x; t[1] = (_Float16)x0.y; t[2] = (_Float16)x0.z; t[3] = (_Float16)x0.w;
      t[4] = (_Float16)x1.x; t[5] = (_Float16)x1.y; t[6] = (_Float16)x1.z; t[7] = (_Float16)x1.w;
      aF[mt] = t;
    }
#pragma unroll
    for (int nt = 0; nt < 4; ++nt)
      bF[nt] = *(const h8v*)(BT + (size_t)(colBase + nt * 16 + lm) * K + k);
#pragma unroll
    for (int mt = 0; mt < 4; ++mt)
#pragma unroll
      for (int nt = 0; nt < 4; ++nt)
        acc[mt][nt] = __builtin_amdgcn_mfma_f32_16x16x32_f16(aF[mt], bF[nt], acc[mt][nt], 0, 0, 0);
  }
#pragma unroll
  for (int nt = 0; nt < 4; ++nt) {
    int col = colBase + nt * 16 + lm;
    float bv = (col < biasLen) ? bias[col] : 0.0f;
#pragma unroll
    for (int mt = 0; mt < 4; ++mt) {
#pragma unroll
      for (int i = 0; i < 4; ++i) {
        int row = rowBase + mt * 16 + q * 4 + i;   // C/D: col=lane&15, row=q*4+reg
        if (row < NN) C[(size_t)row * Ntot + col] = f2h(acc[mt][nt][i] + bv);
      }
    }
  }
}

// ================= edge GEMM: 128 edges x NT cols per 512-thr block (f16) ==============
// 8 waves = 2 row-groups (64 edges each) x 4 col-groups (NT/4 cols each).
// LDS A-tile (128 x KT, relu(a_dst+b_src) via v_pk_add_f16+v_pk_max_f16) shared by
// all 8 waves. Per k-tile: issue bF loads -> convert prefetched gathers -> LDS (dbuf)
// -> prefetch next tile's gathers -> barrier -> MFMA (f16).
// __launch_bounds__(512, 4): 128-reg budget. With 512-thr blocks occupancy is
// quantized in 8-wave chunks -> need total regs <=128 for 2 blocks/CU (round 7's
// 140-reg build got 1 block/CU, 22% occupancy, latency-bound). The split-asm
// cvt_pair (no early-clobber) restores the round-4 register footprint.
// Epilogue: per-row-group segment table; ONE memory op per (col, distinct dst):
// plain store for group-interior dsts, atomicMax for group/block-boundary dsts.
template<int K, int NT>
__global__ void __launch_bounds__(512, 4)
edge_gemm_pf(const short* __restrict__ AB, const short* __restrict__ BTf,
             const float* __restrict__ bias,
             const int* __restrict__ sSrc, const int* __restrict__ sDst,
             int* __restrict__ y) {
  constexpr int ROWS = 128;         // edges per block
  constexpr int KT = 64;            // k-tile
  constexpr int KTP = 72;           // LDS pitch (shorts): breaks bank alignment, keeps 16B
  constexpr int TILES = K / KT;
  constexpr int WCOLS = NT / 4;     // cols per wave (4 col-groups)
  constexpr int NTL = WCOLS / 16;
  __shared__ __align__(16) short hA[2][ROWS * KTP];  // 2 x 18432 B
  __shared__ int srcS[ROWS], dstS[ROWS];
  __shared__ int segDst[2][64];     // dst node per segment, per row-group
  __shared__ int segAtm[2][64];     // 1 = boundary dst (atomic), 0 = interior (store)
  __shared__ __align__(4) unsigned char rowSidC[ROWS]; // per-row segment id within group
  __shared__ int segD[2];

  const int tid = threadIdx.x;
  const int eBase = blockIdx.x * ROWS;
  const int wave = tid >> 6, lane = tid & 63, lm = lane & 15, q = lane >> 4;
  const int cg = wave & 3, rg = wave >> 2;
  const int cBase = cg * WCOLS;
  const int rg64 = rg * 64;

  if (tid < ROWS) { srcS[tid] = sSrc[eBase + tid]; dstS[tid] = sDst[eBase + tid]; }
  __syncthreads();

  // per-thread staging coords: 2 chunks (rows r0 and r0+64), fixed column chunk kc0
  const int r0 = tid >> 3, kc0 = (tid & 7) * 8;
  const int r1 = r0 + 64;
  const size_t dO0 = (size_t)dstS[r0] * (2 * K) + kc0;
  const size_t sO0 = (size_t)srcS[r0] * (2 * K) + K + kc0;
  const size_t dO1 = (size_t)dstS[r1] * (2 * K) + kc0;
  const size_t sO1 = (size_t)srcS[r1] * (2 * K) + K + kc0;

  // prologue: issue tile-0 gather prefetch FIRST (latency hidden under table build)
  uint4 av0 = *(const uint4*)(AB + dO0);
  uint4 bv0 = *(const uint4*)(AB + sO0);
  uint4 av1 = *(const uint4*)(AB + dO1);
  uint4 bv1 = *(const uint4*)(AB + sO1);

  // ---- waves 0,1: build per-row-group segment tables (consumed in epilogue;
  // visibility guaranteed by the main-loop __syncthreads) ----
  if (tid < 2 * 64) {
    const int w = tid >> 6;          // row-group
    const int r = tid & 63;          // row within group
    const int row = tid;             // global row in block (group0: 0-63, group1: 64-127)
    int d = dstS[row];
    int prev = (r == 0) ? -1 : dstS[row - 1];
    bool flag = (r == 0) || (d != prev);
    unsigned long long mask = __ballot(flag);
    int Dtot = __popcll(mask);
    int sid = __popcll(mask & (0xFFFFFFFFFFFFFFFFull >> (63 - r))) - 1;
    rowSidC[row] = (unsigned char)sid;
    if (r == 0) segD[w] = Dtot;
    if (flag) {
      // neighbor dst just before this group / just after this group
      int prevOut = (w == 1) ? dstS[63]
                             : ((eBase > 0) ? sDst[eBase - 1] : -1);
      int nextOut = (w == 0) ? dstS[64]
                             : ((eBase + ROWS < NE) ? sDst[eBase + ROWS] : -1);
      bool atm = false;
      if (sid == 0 && prevOut == d) atm = true;
      if (sid == Dtot - 1 && nextOut == d) atm = true;
      segDst[w][sid] = d;
      segAtm[w][sid] = atm ? 1 : 0;
    }
  }

  f4v acc[4][NTL] = {};

  for (int t = 0; t < TILES; ++t) {
    // 1. issue s=0 bF loads (fly during convert + barrier)
    h8v bF0[NTL];
#pragma unroll
    for (int nt = 0; nt < NTL; ++nt)
      bF0[nt] = *(const h8v*)(BTf + (size_t)(t * 2) * (NT * 32) +
                              (cBase + nt * 16 + lm) * 32 + q * 8);
    // 2. convert prefetched gathers -> LDS (double-buffered); 2 VALU ops per word
    short* hbuf = hA[t & 1];
    {
      uint4 o;
      o.x = cvt_pair(av0.x, bv0.x); o.y = cvt_pair(av0.y, bv0.y);
      o.z = cvt_pair(av0.z, bv0.z); o.w = cvt_pair(av0.w, bv0.w);
      *(uint4*)(&hbuf[r0 * KTP + kc0]) = o;
      uint4 o1;
      o1.x = cvt_pair(av1.x, bv1.x); o1.y = cvt_pair(av1.y, bv1.y);
      o1.z = cvt_pair(av1.z, bv1.z); o1.w = cvt_pair(av1.w, bv1.w);
      *(uint4*)(&hbuf[r1 * KTP + kc0]) = o1;
    }
    // 3. prefetch next tile's gathers (land during barrier + MFMA below)
    if (t + 1 < TILES) {
      const int kn = (t + 1) * KT;
      av0 = *(const uint4*)(AB + dO0 + kn);
      bv0 = *(const uint4*)(AB + sO0 + kn);
      av1 = *(const uint4*)(AB + dO1 + kn);
      bv1 = *(const uint4*)(AB + sO1 + kn);
    }
    __syncthreads();
    // 4a. s=0 MFMA: aF per-mt from LDS, bF0 from regs
    {
      const int kl = q * 8;
      __builtin_amdgcn_s_setprio(1);
#pragma unroll
      for (int mt = 0; mt < 4; ++mt) {
        h8v aF = *(const h8v*)(&hbuf[(rg64 + mt * 16 + lm) * KTP + kl]);
#pragma unroll
        for (int nt = 0; nt < NTL; ++nt)
          acc[mt][nt] = __builtin_amdgcn_mfma_f32_16x16x32_f16(aF, bF0[nt], acc[mt][nt], 0, 0, 0);
      }
      __builtin_amdgcn_s_setprio(0);
    }
    // 4b. s=1: load bF1 here (keeps bF register footprint at NTL)
    {
      h8v bF1[NTL];
#pragma unroll
      for (int nt = 0; nt < NTL; ++nt)
        bF1[nt] = *(const h8v*)(BTf + (size_t)(t * 2 + 1) * (NT * 32) +
                                (cBase + nt * 16 + lm) * 32 + q * 8);
      const int kl = 32 + q * 8;
      __builtin_amdgcn_s_setprio(1);
#pragma unroll
      for (int mt = 0; mt < 4; ++mt) {
        h8v aF = *(const h8v*)(&hbuf[(rg64 + mt * 16 + lm) * KTP + kl]);
#pragma unroll
        for (int nt = 0; nt < NTL; ++nt)
          acc[mt][nt] = __builtin_amdgcn_mfma_f32_16x16x32_f16(aF, bF1[nt], acc[mt][nt], 0, 0, 0);
      }
      __builtin_amdgcn_s_setprio(0);
    }
  }

  // ---- epilogue: segmented max per column within this wave's row-group ----
  const int D = segD[rg];
  int sid[4][4];
#pragma unroll
  for (int mt = 0; mt < 4; ++mt) {
    unsigned pk = *(const unsigned*)(&rowSidC[rg64 + mt * 16 + q * 4]);  // 4B aligned
#pragma unroll
    for (int i = 0; i < 4; ++i) sid[mt][i] = (int)((pk >> (8 * i)) & 255u);
  }
#pragma unroll
  for (int nt = 0; nt < NTL; ++nt) {
    const int col = cBase + nt * 16 + lm;
    const float bvv = bias[col];
    for (int s = 0; s < D; ++s) {
      float m = -1e30f;
#pragma unroll
      for (int mt = 0; mt < 4; ++mt)
#pragma unroll
        for (int i = 0; i < 4; ++i)
          m = fmaxf(m, sid[mt][i] == s ? acc[mt][nt][i] : -1e30f);
      // reduce across the 4 q-lanes holding this column
      m = fmaxf(m, __shfl_xor(m, 16));
      m = fmaxf(m, __shfl_xor(m, 32));
      if (q == 0) {
        float v = m + bvv;
        int* addr = &y[(size_t)segDst[rg][s] * NT + col];
        if (segAtm[rg][s]) {
          if (v > 0.f) atomicMax(addr, __float_as_int(v));
        } else {
          *addr = __float_as_int(fmaxf(v, 0.f));   // group owns this dst: plain store
        }
      }
    }
  }
}

// ================= head: one wave per node =================
__global__ void __launch_bounds__(64)
head_kernel(const float* __restrict__ y2, const float* __restrict__ W3,
            const float* __restrict__ b3, const float* __restrict__ W4,
            const float* __restrict__ b4, float* __restrict__ out) {
  const int n = blockIdx.x, j = threadIdx.x;
  const float* yr = y2 + (size_t)n * 128;
  float acc = 0.f;
#pragma unroll
  for (int k = 0; k < 128; ++k) acc += yr[k] * W3[k * 64 + j];
  acc += b3[j];
  float h = acc > 0.f ? acc : 0.f;
  float p = h * W4[j];
#pragma unroll
  for (int off = 32; off; off >>= 1) p += __shfl_down(p, off);
  if (j == 0) {
    float z = p + b4[0];
    out[n] = 1.f / (1.f + expf(-z));
  }
}

__global__ void diag_kernel(float* out, float v) { out[0] = v; }

extern "C" void kernel_launch(void* const* d_in, const int* in_sizes, int n_in,
                              void* d_out, int out_size, void* d_ws, size_t ws_size,
                              hipStream_t stream) {
  const float* x   = (const float*)d_in[0];
  const int*   ei  = (const int*)d_in[1];
  const float* W1a = (const float*)d_in[2];
  const float* b1a = (const float*)d_in[3];
  const float* W2a = (const float*)d_in[4];
  const float* b2a = (const float*)d_in[5];
  const float* W1b = (const float*)d_in[6];
  const float* b1b = (const float*)d_in[7];
  const float* W2b = (const float*)d_in[8];
  const float* b2b = (const float*)d_in[9];
  const float* W3  = (const float*)d_in[10];
  const float* b3  = (const float*)d_in[11];
  const float* W4  = (const float*)d_in[12];
  const float* b4  = (const float*)d_in[13];

  // workspace layout (peak 34,211,968 B)
  char* ws = (char*)d_ws;
  short* Wp1T = (short*)(ws + 0);          //  262144 B [1024][128]
  short* Wp2T = (short*)(ws + 262144);     //  262144 B [512][256]
  short* BTf1 = (short*)(ws + 524288);     //  262144 B W2a^T fragment layout
  short* BTf2 = (short*)(ws + 786432);     //   65536 B W2b^T fragment layout
  short* A1B1 = (short*)(ws + 851968);     // 20480000 B [10000][1024] f16
  short* A2B2 = (short*)(ws + 851968);     // reuse (A1B1 dead): [10000][512]
  int*   Y1   = (int*)(ws + 21331968);     // 10240000 B [10000][256] fp32
  int*   Y2   = (int*)(ws + 21331968);     // reuse (Y1 dead): [10000][128] fp32
  int*   cnt  = (int*)(ws + 31571968);     //    40000 B
  int*   cur  = (int*)(ws + 31611968);     //    40000 B
  int*   sSrc = (int*)(ws + 31651968);     //  1280000 B
  int*   sDst = (int*)(ws + 32931968);     //  1280000 B

  if (ws_size < 34211968) {                // diagnostic: encode ws_size in the absmax error
    diag_kernel<<<1, 1, 0, stream>>>((float*)d_out, (float)ws_size);
    return;
  }

  // ---- counting sort by dst ----
  hipMemsetAsync(cnt, 0, 40000, stream);
  hist_kernel<<<1250, 256, 0, stream>>>(ei, cnt);
  scan_kernel<<<1, 1024, 0, stream>>>(cnt, cur);
  scatter_kernel<<<1250, 256, 0, stream>>>(ei, cur, sSrc, sDst);

  prep_weights<<<1664, 256, 0, stream>>>(W1a, W1b, W2a, W2b, Wp1T, Wp2T, BTf1, BTf2);

  // EdgeConv 1
  node_gemm<128><<<dim3(157, 4), 256, 0, stream>>>(x, Wp1T, b1a, 512, A1B1, 1024);
  hipMemsetAsync(Y1, 0, (size_t)NN * 256 * 4, stream);
  edge_gemm_pf<512, 256><<<2500, 512, 0, stream>>>(A1B1, BTf1, b2a, sSrc, sDst, Y1);

  // EdgeConv 2 (A2B2 overwrites dead A1B1; Y2 memset AFTER node_gemm reads aliased Y1)
  node_gemm<256><<<dim3(157, 2), 256, 0, stream>>>((const float*)Y1, Wp2T, b1b, 256, A2B2, 512);
  hipMemsetAsync(Y2, 0, (size_t)NN * 128 * 4, stream);
  edge_gemm_pf<256, 128><<<2500, 512, 0, stream>>>(A2B2, BTf2, b2b, sSrc, sDst, Y2);

  // Head
  head_kernel<<<NN, 64, 0, stream>>>((const float*)Y2, W3, b3, W4, b4, (float*)d_out);
}

// Round 11
// 403.958 us; speedup vs baseline: 1.0824x; 1.0824x over previous
//
#include <hip/hip_runtime.h>
#include <math.h>

#define NN 10000
#define NE 320000

typedef __attribute__((ext_vector_type(8))) short s8v;       // 8x16-bit (4 VGPRs)
typedef __attribute__((ext_vector_type(8))) _Float16 h8v;    // 8 f16 (4 VGPRs) MFMA frag
typedef __attribute__((ext_vector_type(4))) float f4v;       // MFMA accumulator

__device__ __forceinline__ short f2h(float f) {
  _Float16 h = (_Float16)f;            // v_cvt_f16_f32 (RNE)
  short s; __builtin_memcpy(&s, &h, 2); return s;
}
// relu(f16a + f16b) on 8 packed f16 lanes: native clang vector arithmetic lowers
// to 4x v_pk_add_f16 + 4x v_pk_max_f16 with FULL register-allocator freedom.
// No header intrinsics (ROCm 7.2 has no vector __hmax2 overload) and no inline
// asm (rounds 6-9: asm operand pinning cost ~6-12 VGPRs -> scratch spill at the
// exact-fit 128-reg budget of __launch_bounds__(512,4)).
__device__ __forceinline__ uint4 cvt8(uint4 ua, uint4 ub) {
  h8v a, b;
  __builtin_memcpy(&a, &ua, 16);
  __builtin_memcpy(&b, &ub, 16);
  h8v r = a + b;
  r = __builtin_elementwise_max(r, (h8v)(_Float16)0.0f);
  uint4 o; __builtin_memcpy(&o, &r, 16);
  return o;
}

// ================= edge sort by dst (counting sort) =================
__global__ void hist_kernel(const int* __restrict__ ei, int* __restrict__ cnt) {
  int e = blockIdx.x * 256 + threadIdx.x;
  if (e < NE) atomicAdd(&cnt[ei[NE + e]], 1);
}

__global__ void __launch_bounds__(1024)
scan_kernel(const int* __restrict__ cnt, int* __restrict__ cur) {
  __shared__ int part[1024];
  const int t = threadIdx.x;
  const int base = t * 10;
  int local[10];
  int s = 0;
#pragma unroll
  for (int u = 0; u < 10; ++u) {
    int c = (base + u < NN) ? cnt[base + u] : 0;
    local[u] = s; s += c;
  }
  part[t] = s;
  __syncthreads();
  for (int off = 1; off < 1024; off <<= 1) {
    int v = part[t];
    int w = (t >= off) ? part[t - off] : 0;
    __syncthreads();
    part[t] = v + w;
    __syncthreads();
  }
  int excl = (t == 0) ? 0 : part[t - 1];
#pragma unroll
  for (int u = 0; u < 10; ++u)
    if (base + u < NN) cur[base + u] = excl + local[u];
}

__global__ void scatter_kernel(const int* __restrict__ ei, int* __restrict__ cur,
                               int* __restrict__ sSrc, int* __restrict__ sDst) {
  int e = blockIdx.x * 256 + threadIdx.x;
  if (e < NE) {
    int d = ei[NE + e];
    int p = atomicAdd(&cur[d], 1);
    sSrc[p] = ei[e];
    sDst[p] = d;
  }
}

// ================= prep: combined/transposed weights, fp32 -> f16 =================
// Wp1T [1024][128], Wp2T [512][256] : node-GEMM layouts (row n, col k)
// BTf1 / BTf2 : edge-GEMM fragment layout: idx = (k>>5)*(NT*32) + n*32 + (k&31)
__global__ void prep_weights(const float* __restrict__ W1a, const float* __restrict__ W1b,
                             const float* __restrict__ W2a, const float* __restrict__ W2b,
                             short* __restrict__ Wp1T, short* __restrict__ Wp2T,
                             short* __restrict__ BTf1, short* __restrict__ BTf2) {
  int i = blockIdx.x * 256 + threadIdx.x;
  if (i < 131072) {                        // Wp1T[j][k], j<1024, k<128
    int j = i >> 7, k = i & 127;
    float v;
    if (j < 512) v = W1a[k * 512 + j] - W1a[(k + 128) * 512 + j];
    else         v = W1a[(k + 128) * 512 + (j - 512)];
    Wp1T[i] = f2h(v);
  } else if (i < 262144) {                 // Wp2T[j][k], j<512, k<256
    int t = i - 131072;
    int j = t >> 8, k = t & 255;
    float v;
    if (j < 256) v = W1b[k * 256 + j] - W1b[(k + 256) * 256 + j];
    else         v = W1b[(k + 256) * 256 + (j - 256)];
    Wp2T[t] = f2h(v);
  } else if (i < 393216) {                 // BTf1: W2a^T fragment layout (NT=256, K=512)
    int t = i - 262144;
    int n = t >> 9, k = t & 511;
    BTf1[(k >> 5) * 8192 + n * 32 + (k & 31)] = f2h(W2a[k * 256 + n]);
  } else if (i < 425984) {                 // BTf2: W2b^T fragment layout (NT=128, K=256)
    int t = i - 393216;
    int n = t >> 8, k = t & 255;
    BTf2[(k >> 5) * 4096 + n * 32 + (k & 31)] = f2h(W2b[k * 128 + n]);
  }
}

// ================= node GEMM: C[NN][Ntot](f16) = A[NN][K](fp32) @ BT^T + bias ===========
template<int K>
__global__ void __launch_bounds__(256)
node_gemm(const float* __restrict__ A, const short* __restrict__ BT,
          const float* __restrict__ bias, int biasLen,
          short* __restrict__ C, int Ntot) {
  const int rowBase = blockIdx.x * 64;
  const int wave = threadIdx.x >> 6, lane = threadIdx.x & 63;
  const int colBase = blockIdx.y * 256 + wave * 64;
  const int lm = lane & 15, q = lane >> 4;
  f4v acc[4][4] = {};
  int arow[4];
#pragma unroll
  for (int mt = 0; mt < 4; ++mt) {
    int r = rowBase + mt * 16 + lm;
    arow[mt] = r < NN ? r : NN - 1;        // clamp; stores guarded below
  }
  for (int kk = 0; kk < K; kk += 32) {
    const int k = kk + q * 8;
    h8v aF[4], bF[4];
#pragma unroll
    for (int mt = 0; mt < 4; ++mt) {
      const float4* ap = (const float4*)(A + (size_t)arow[mt] * K + k);
      float4 x0 = ap[0], x1 = ap[1];
      h8v t;
      t[0] = (_Float16)x0.x; t[1] = (_Float16)x0.y; t[2] = (_Float16)x0.z; t[3] = (_Float16)x0.w;
      t[4] = (_Float16)x1.x; t[5] = (_Float16)x1.y; t[6] = (_Float16)x1.z; t[7] = (_Float16)x1.w;
      aF[mt] = t;
    }
#pragma unroll
    for (int nt = 0; nt < 4; ++nt)
      bF[nt] = *(const h8v*)(BT + (size_t)(colBase + nt * 16 + lm) * K + k);
#pragma unroll
    for (int mt = 0; mt < 4; ++mt)
#pragma unroll
      for (int nt = 0; nt < 4; ++nt)
        acc[mt][nt] = __builtin_amdgcn_mfma_f32_16x16x32_f16(aF[mt], bF[nt], acc[mt][nt], 0, 0, 0);
  }
#pragma unroll
  for (int nt = 0; nt < 4; ++nt) {
    int col = colBase + nt * 16 + lm;
    float bv = (col < biasLen) ? bias[col] : 0.0f;
#pragma unroll
    for (int mt = 0; mt < 4; ++mt) {
#pragma unroll
      for (int i = 0; i < 4; ++i) {
        int row = rowBase + mt * 16 + q * 4 + i;   // C/D: col=lane&15, row=q*4+reg
        if (row < NN) C[(size_t)row * Ntot + col] = f2h(acc[mt][nt][i] + bv);
      }
    }
  }
}

// ================= edge GEMM: 128 edges x NT cols per 512-thr block (f16) ==============
// 8 waves = 2 row-groups (64 edges each) x 4 col-groups (NT/4 cols each).
// LDS A-tile (128 x KT, relu(a_dst+b_src) via native f16 vector ops) shared by
// all 8 waves. Per k-tile: issue bF loads -> convert prefetched gathers -> LDS (dbuf)
// -> prefetch next tile's gathers -> barrier -> MFMA (f16).
// __launch_bounds__(512, 4): 128-reg budget, EXACT fit (64 arch + 64 acc) — no
// headroom for asm-pinned values (rounds 6/9 spilled acc to scratch: WRITE 343/228MB).
// Pure-expression cvt8 restores the bf16-build allocator behavior.
// Epilogue: per-row-group segment table; ONE memory op per (col, distinct dst):
// plain store for group-interior dsts, atomicMax for group/block-boundary dsts.
template<int K, int NT>
__global__ void __launch_bounds__(512, 4)
edge_gemm_pf(const short* __restrict__ AB, const short* __restrict__ BTf,
             const float* __restrict__ bias,
             const int* __restrict__ sSrc, const int* __restrict__ sDst,
             int* __restrict__ y) {
  constexpr int ROWS = 128;         // edges per block
  constexpr int KT = 64;            // k-tile
  constexpr int KTP = 72;           // LDS pitch (shorts): breaks bank alignment, keeps 16B
  constexpr int TILES = K / KT;
  constexpr int WCOLS = NT / 4;     // cols per wave (4 col-groups)
  constexpr int NTL = WCOLS / 16;
  __shared__ __align__(16) short hA[2][ROWS * KTP];  // 2 x 18432 B
  __shared__ int srcS[ROWS], dstS[ROWS];
  __shared__ int segDst[2][64];     // dst node per segment, per row-group
  __shared__ int segAtm[2][64];     // 1 = boundary dst (atomic), 0 = interior (store)
  __shared__ __align__(4) unsigned char rowSidC[ROWS]; // per-row segment id within group
  __shared__ int segD[2];

  const int tid = threadIdx.x;
  const int eBase = blockIdx.x * ROWS;
  const int wave = tid >> 6, lane = tid & 63, lm = lane & 15, q = lane >> 4;
  const int cg = wave & 3, rg = wave >> 2;
  const int cBase = cg * WCOLS;
  const int rg64 = rg * 64;

  if (tid < ROWS) { srcS[tid] = sSrc[eBase + tid]; dstS[tid] = sDst[eBase + tid]; }
  __syncthreads();

  // per-thread staging coords: 2 chunks (rows r0 and r0+64), fixed column chunk kc0
  const int r0 = tid >> 3, kc0 = (tid & 7) * 8;
  const int r1 = r0 + 64;
  const size_t dO0 = (size_t)dstS[r0] * (2 * K) + kc0;
  const size_t sO0 = (size_t)srcS[r0] * (2 * K) + K + kc0;
  const size_t dO1 = (size_t)dstS[r1] * (2 * K) + kc0;
  const size_t sO1 = (size_t)srcS[r1] * (2 * K) + K + kc0;

  // prologue: issue tile-0 gather prefetch FIRST (latency hidden under table build)
  uint4 av0 = *(const uint4*)(AB + dO0);
  uint4 bv0 = *(const uint4*)(AB + sO0);
  uint4 av1 = *(const uint4*)(AB + dO1);
  uint4 bv1 = *(const uint4*)(AB + sO1);

  // ---- waves 0,1: build per-row-group segment tables (consumed in epilogue;
  // visibility guaranteed by the main-loop __syncthreads) ----
  if (tid < 2 * 64) {
    const int w = tid >> 6;          // row-group
    const int r = tid & 63;          // row within group
    const int row = tid;             // global row in block (group0: 0-63, group1: 64-127)
    int d = dstS[row];
    int prev = (r == 0) ? -1 : dstS[row - 1];
    bool flag = (r == 0) || (d != prev);
    unsigned long long mask = __ballot(flag);
    int Dtot = __popcll(mask);
    int sid = __popcll(mask & (0xFFFFFFFFFFFFFFFFull >> (63 - r))) - 1;
    rowSidC[row] = (unsigned char)sid;
    if (r == 0) segD[w] = Dtot;
    if (flag) {
      // neighbor dst just before this group / just after this group
      int prevOut = (w == 1) ? dstS[63]
                             : ((eBase > 0) ? sDst[eBase - 1] : -1);
      int nextOut = (w == 0) ? dstS[64]
                             : ((eBase + ROWS < NE) ? sDst[eBase + ROWS] : -1);
      bool atm = false;
      if (sid == 0 && prevOut == d) atm = true;
      if (sid == Dtot - 1 && nextOut == d) atm = true;
      segDst[w][sid] = d;
      segAtm[w][sid] = atm ? 1 : 0;
    }
  }

  f4v acc[4][NTL] = {};

  for (int t = 0; t < TILES; ++t) {
    // 1. issue s=0 bF loads (fly during convert + barrier)
    h8v bF0[NTL];
#pragma unroll
    for (int nt = 0; nt < NTL; ++nt)
      bF0[nt] = *(const h8v*)(BTf + (size_t)(t * 2) * (NT * 32) +
                              (cBase + nt * 16 + lm) * 32 + q * 8);
    // 2. convert prefetched gathers -> LDS (double-buffered); 2 pk-ops per word
    short* hbuf = hA[t & 1];
    {
      *(uint4*)(&hbuf[r0 * KTP + kc0]) = cvt8(av0, bv0);
      *(uint4*)(&hbuf[r1 * KTP + kc0]) = cvt8(av1, bv1);
    }
    // 3. prefetch next tile's gathers (land during barrier + MFMA below)
    if (t + 1 < TILES) {
      const int kn = (t + 1) * KT;
      av0 = *(const uint4*)(AB + dO0 + kn);
      bv0 = *(const uint4*)(AB + sO0 + kn);
      av1 = *(const uint4*)(AB + dO1 + kn);
      bv1 = *(const uint4*)(AB + sO1 + kn);
    }
    __syncthreads();
    // 4a. s=0 MFMA: aF per-mt from LDS, bF0 from regs
    {
      const int kl = q * 8;
      __builtin_amdgcn_s_setprio(1);
#pragma unroll
      for (int mt = 0; mt < 4; ++mt) {
        h8v aF = *(const h8v*)(&hbuf[(rg64 + mt * 16 + lm) * KTP + kl]);
#pragma unroll
        for (int nt = 0; nt < NTL; ++nt)
          acc[mt][nt] = __builtin_amdgcn_mfma_f32_16x16x32_f16(aF, bF0[nt], acc[mt][nt], 0, 0, 0);
      }
      __builtin_amdgcn_s_setprio(0);
    }
    // 4b. s=1: load bF1 here (keeps bF register footprint at NTL)
    {
      h8v bF1[NTL];
#pragma unroll
      for (int nt = 0; nt < NTL; ++nt)
        bF1[nt] = *(const h8v*)(BTf + (size_t)(t * 2 + 1) * (NT * 32) +
                                (cBase + nt * 16 + lm) * 32 + q * 8);
      const int kl = 32 + q * 8;
      __builtin_amdgcn_s_setprio(1);
#pragma unroll
      for (int mt = 0; mt < 4; ++mt) {
        h8v aF = *(const h8v*)(&hbuf[(rg64 + mt * 16 + lm) * KTP + kl]);
#pragma unroll
        for (int nt = 0; nt < NTL; ++nt)
          acc[mt][nt] = __builtin_amdgcn_mfma_f32_16x16x32_f16(aF, bF1[nt], acc[mt][nt], 0, 0, 0);
      }
      __builtin_amdgcn_s_setprio(0);
    }
  }

  // ---- epilogue: segmented max per column within this wave's row-group ----
  const int D = segD[rg];
  int sid[4][4];
#pragma unroll
  for (int mt = 0; mt < 4; ++mt) {
    unsigned pk = *(const unsigned*)(&rowSidC[rg64 + mt * 16 + q * 4]);  // 4B aligned
#pragma unroll
    for (int i = 0; i < 4; ++i) sid[mt][i] = (int)((pk >> (8 * i)) & 255u);
  }
#pragma unroll
  for (int nt = 0; nt < NTL; ++nt) {
    const int col = cBase + nt * 16 + lm;
    const float bvv = bias[col];
    for (int s = 0; s < D; ++s) {
      float m = -1e30f;
#pragma unroll
      for (int mt = 0; mt < 4; ++mt)
#pragma unroll
        for (int i = 0; i < 4; ++i)
          m = fmaxf(m, sid[mt][i] == s ? acc[mt][nt][i] : -1e30f);
      // reduce across the 4 q-lanes holding this column
      m = fmaxf(m, __shfl_xor(m, 16));
      m = fmaxf(m, __shfl_xor(m, 32));
      if (q == 0) {
        float v = m + bvv;
        int* addr = &y[(size_t)segDst[rg][s] * NT + col];
        if (segAtm[rg][s]) {
          if (v > 0.f) atomicMax(addr, __float_as_int(v));
        } else {
          *addr = __float_as_int(fmaxf(v, 0.f));   // group owns this dst: plain store
        }
      }
    }
  }
}

// ================= head: one wave per node =================
__global__ void __launch_bounds__(64)
head_kernel(const float* __restrict__ y2, const float* __restrict__ W3,
            const float* __restrict__ b3, const float* __restrict__ W4,
            const float* __restrict__ b4, float* __restrict__ out) {
  const int n = blockIdx.x, j = threadIdx.x;
  const float* yr = y2 + (size_t)n * 128;
  float acc = 0.f;
#pragma unroll
  for (int k = 0; k < 128; ++k) acc += yr[k] * W3[k * 64 + j];
  acc += b3[j];
  float h = acc > 0.f ? acc : 0.f;
  float p = h * W4[j];
#pragma unroll
  for (int off = 32; off; off >>= 1) p += __shfl_down(p, off);
  if (j == 0) {
    float z = p + b4[0];
    out[n] = 1.f / (1.f + expf(-z));
  }
}

__global__ void diag_kernel(float* out, float v) { out[0] = v; }

extern "C" void kernel_launch(void* const* d_in, const int* in_sizes, int n_in,
                              void* d_out, int out_size, void* d_ws, size_t ws_size,
                              hipStream_t stream) {
  const float* x   = (const float*)d_in[0];
  const int*   ei  = (const int*)d_in[1];
  const float* W1a = (const float*)d_in[2];
  const float* b1a = (const float*)d_in[3];
  const float* W2a = (const float*)d_in[4];
  const float* b2a = (const float*)d_in[5];
  const float* W1b = (const float*)d_in[6];
  const float* b1b = (const float*)d_in[7];
  const float* W2b = (const float*)d_in[8];
  const float* b2b = (const float*)d_in[9];
  const float* W3  = (const float*)d_in[10];
  const float* b3  = (const float*)d_in[11];
  const float* W4  = (const float*)d_in[12];
  const float* b4  = (const float*)d_in[13];

  // workspace layout (peak 34,211,968 B)
  char* ws = (char*)d_ws;
  short* Wp1T = (short*)(ws + 0);          //  262144 B [1024][128]
  short* Wp2T = (short*)(ws + 262144);     //  262144 B [512][256]
  short* BTf1 = (short*)(ws + 524288);     //  262144 B W2a^T fragment layout
  short* BTf2 = (short*)(ws + 786432);     //   65536 B W2b^T fragment layout
  short* A1B1 = (short*)(ws + 851968);     // 20480000 B [10000][1024] f16
  short* A2B2 = (short*)(ws + 851968);     // reuse (A1B1 dead): [10000][512]
  int*   Y1   = (int*)(ws + 21331968);     // 10240000 B [10000][256] fp32
  int*   Y2   = (int*)(ws + 21331968);     // reuse (Y1 dead): [10000][128] fp32
  int*   cnt  = (int*)(ws + 31571968);     //    40000 B
  int*   cur  = (int*)(ws + 31611968);     //    40000 B
  int*   sSrc = (int*)(ws + 31651968);     //  1280000 B
  int*   sDst = (int*)(ws + 32931968);     //  1280000 B

  if (ws_size < 34211968) {                // diagnostic: encode ws_size in the absmax error
    diag_kernel<<<1, 1, 0, stream>>>((float*)d_out, (float)ws_size);
    return;
  }

  // ---- counting sort by dst ----
  hipMemsetAsync(cnt, 0, 40000, stream);
  hist_kernel<<<1250, 256, 0, stream>>>(ei, cnt);
  scan_kernel<<<1, 1024, 0, stream>>>(cnt, cur);
  scatter_kernel<<<1250, 256, 0, stream>>>(ei, cur, sSrc, sDst);

  prep_weights<<<1664, 256, 0, stream>>>(W1a, W1b, W2a, W2b, Wp1T, Wp2T, BTf1, BTf2);

  // EdgeConv 1
  node_gemm<128><<<dim3(157, 4), 256, 0, stream>>>(x, Wp1T, b1a, 512, A1B1, 1024);
  hipMemsetAsync(Y1, 0, (size_t)NN * 256 * 4, stream);
  edge_gemm_pf<512, 256><<<2500, 512, 0, stream>>>(A1B1, BTf1, b2a, sSrc, sDst, Y1);

  // EdgeConv 2 (A2B2 overwrites dead A1B1; Y2 memset AFTER node_gemm reads aliased Y1)
  node_gemm<256><<<dim3(157, 2), 256, 0, stream>>>((const float*)Y1, Wp2T, b1b, 256, A2B2, 512);
  hipMemsetAsync(Y2, 0, (size_t)NN * 128 * 4, stream);
  edge_gemm_pf<256, 128><<<2500, 512, 0, stream>>>(A2B2, BTf2, b2b, sSrc, sDst, Y2);

  // Head
  head_kernel<<<NN, 64, 0, stream>>>((const float*)Y2, W3, b3, W4, b4, (float*)d_out);
}

// Round 12
// 394.720 us; speedup vs baseline: 1.1078x; 1.0234x over previous
//
#include <hip/hip_runtime.h>
#include <hip/hip_bf16.h>
#include <math.h>

#define NN 10000
#define NE 320000

typedef __attribute__((ext_vector_type(8))) short s8v;   // 8 bf16 (4 VGPRs)
typedef __attribute__((ext_vector_type(4))) float f4v;   // MFMA accumulator

__device__ __forceinline__ short f2bf(float f) {
  unsigned u = __float_as_uint(f);
  u = u + 0x7fffu + ((u >> 16) & 1u);   // RNE
  return (short)(u >> 16);
}
// relu(bf16a + bf16b) for a packed pair, RNE pack (exact: fp32 add of two bf16s)
__device__ __forceinline__ unsigned cvt_pair(unsigned wa, unsigned wb) {
  float a0 = __uint_as_float(wa << 16);
  float a1 = __uint_as_float(wa & 0xFFFF0000u);
  float b0 = __uint_as_float(wb << 16);
  float b1 = __uint_as_float(wb & 0xFFFF0000u);
  float s0 = fmaxf(a0 + b0, 0.f);
  float s1 = fmaxf(a1 + b1, 0.f);
  __hip_bfloat162 h = __float22bfloat162_rn(float2{s0, s1});
  unsigned u; __builtin_memcpy(&u, &h, 4);
  return u;
}

// Barrier that does NOT drain vmcnt. __syncthreads() emits s_waitcnt vmcnt(0)
// before s_barrier (m97 asm evidence), which serializes a FULL gather round-trip
// (~450-900 cy, L3/HBM) at every k-tile because the t+1 prefetches are issued
// just before the barrier. lgkmcnt(0) alone orders all LDS traffic (ds_write
// AND ds_read), which is what the barrier semantically needs here; global loads
// have register destinations and their consumers get compiler-counted vmcnt
// waits. Double-buffered hA gives 2-barrier separation before buffer reuse.
__device__ __forceinline__ void barrier_lgkm_only() {
  asm volatile("s_waitcnt lgkmcnt(0)" ::: "memory");
  __builtin_amdgcn_s_barrier();
}

// ================= edge sort by dst (counting sort) =================
__global__ void hist_kernel(const int* __restrict__ ei, int* __restrict__ cnt) {
  int e = blockIdx.x * 256 + threadIdx.x;
  if (e < NE) atomicAdd(&cnt[ei[NE + e]], 1);
}

__global__ void __launch_bounds__(1024)
scan_kernel(const int* __restrict__ cnt, int* __restrict__ cur) {
  __shared__ int part[1024];
  const int t = threadIdx.x;
  const int base = t * 10;
  int local[10];
  int s = 0;
#pragma unroll
  for (int u = 0; u < 10; ++u) {
    int c = (base + u < NN) ? cnt[base + u] : 0;
    local[u] = s; s += c;
  }
  part[t] = s;
  __syncthreads();
  for (int off = 1; off < 1024; off <<= 1) {
    int v = part[t];
    int w = (t >= off) ? part[t - off] : 0;
    __syncthreads();
    part[t] = v + w;
    __syncthreads();
  }
  int excl = (t == 0) ? 0 : part[t - 1];
#pragma unroll
  for (int u = 0; u < 10; ++u)
    if (base + u < NN) cur[base + u] = excl + local[u];
}

__global__ void scatter_kernel(const int* __restrict__ ei, int* __restrict__ cur,
                               int* __restrict__ sSrc, int* __restrict__ sDst) {
  int e = blockIdx.x * 256 + threadIdx.x;
  if (e < NE) {
    int d = ei[NE + e];
    int p = atomicAdd(&cur[d], 1);
    sSrc[p] = ei[e];
    sDst[p] = d;
  }
}

// ================= prep: combined/transposed weights, fp32 -> bf16 =================
// Wp1T [1024][128], Wp2T [512][256] : node-GEMM layouts (row n, col k)
// BTf1 / BTf2 : edge-GEMM fragment layout: idx = (k>>5)*(NT*32) + n*32 + (k&31)
__global__ void prep_weights(const float* __restrict__ W1a, const float* __restrict__ W1b,
                             const float* __restrict__ W2a, const float* __restrict__ W2b,
                             short* __restrict__ Wp1T, short* __restrict__ Wp2T,
                             short* __restrict__ BTf1, short* __restrict__ BTf2) {
  int i = blockIdx.x * 256 + threadIdx.x;
  if (i < 131072) {                        // Wp1T[j][k], j<1024, k<128
    int j = i >> 7, k = i & 127;
    float v;
    if (j < 512) v = W1a[k * 512 + j] - W1a[(k + 128) * 512 + j];
    else         v = W1a[(k + 128) * 512 + (j - 512)];
    Wp1T[i] = f2bf(v);
  } else if (i < 262144) {                 // Wp2T[j][k], j<512, k<256
    int t = i - 131072;
    int j = t >> 8, k = t & 255;
    float v;
    if (j < 256) v = W1b[k * 256 + j] - W1b[(k + 256) * 256 + j];
    else         v = W1b[(k + 256) * 256 + (j - 256)];
    Wp2T[t] = f2bf(v);
  } else if (i < 393216) {                 // BTf1: W2a^T fragment layout (NT=256, K=512)
    int t = i - 262144;
    int n = t >> 9, k = t & 511;
    BTf1[(k >> 5) * 8192 + n * 32 + (k & 31)] = f2bf(W2a[k * 256 + n]);
  } else if (i < 425984) {                 // BTf2: W2b^T fragment layout (NT=128, K=256)
    int t = i - 393216;
    int n = t >> 8, k = t & 255;
    BTf2[(k >> 5) * 4096 + n * 32 + (k & 31)] = f2bf(W2b[k * 128 + n]);
  }
}

// ================= node GEMM: C[NN][Ntot](bf16) = A[NN][K](fp32) @ BT^T + bias =================
template<int K>
__global__ void __launch_bounds__(256)
node_gemm(const float* __restrict__ A, const short* __restrict__ BT,
          const float* __restrict__ bias, int biasLen,
          short* __restrict__ C, int Ntot) {
  const int rowBase = blockIdx.x * 64;
  const int wave = threadIdx.x >> 6, lane = threadIdx.x & 63;
  const int colBase = blockIdx.y * 256 + wave * 64;
  const int lm = lane & 15, q = lane >> 4;
  f4v acc[4][4] = {};
  int arow[4];
#pragma unroll
  for (int mt = 0; mt < 4; ++mt) {
    int r = rowBase + mt * 16 + lm;
    arow[mt] = r < NN ? r : NN - 1;        // clamp; stores guarded below
  }
  for (int kk = 0; kk < K; kk += 32) {
    const int k = kk + q * 8;
    s8v aF[4], bF[4];
#pragma unroll
    for (int mt = 0; mt < 4; ++mt) {
      const float4* ap = (const float4*)(A + (size_t)arow[mt] * K + k);
      float4 x0 = ap[0], x1 = ap[1];
      s8v t;
      t[0] = f2bf(x0.x); t[1] = f2bf(x0.y); t[2] = f2bf(x0.z); t[3] = f2bf(x0.w);
      t[4] = f2bf(x1.x); t[5] = f2bf(x1.y); t[6] = f2bf(x1.z); t[7] = f2bf(x1.w);
      aF[mt] = t;
    }
#pragma unroll
    for (int nt = 0; nt < 4; ++nt)
      bF[nt] = *(const s8v*)(BT + (size_t)(colBase + nt * 16 + lm) * K + k);
#pragma unroll
    for (int mt = 0; mt < 4; ++mt)
#pragma unroll
      for (int nt = 0; nt < 4; ++nt)
        acc[mt][nt] = __builtin_amdgcn_mfma_f32_16x16x32_bf16(aF[mt], bF[nt], acc[mt][nt], 0, 0, 0);
  }
#pragma unroll
  for (int nt = 0; nt < 4; ++nt) {
    int col = colBase + nt * 16 + lm;
    float bv = (col < biasLen) ? bias[col] : 0.0f;
#pragma unroll
    for (int mt = 0; mt < 4; ++mt) {
#pragma unroll
      for (int i = 0; i < 4; ++i) {
        int row = rowBase + mt * 16 + q * 4 + i;   // C/D: col=lane&15, row=q*4+reg
        if (row < NN) C[(size_t)row * Ntot + col] = f2bf(acc[mt][nt][i] + bv);
      }
    }
  }
}

// ================= edge GEMM: 128 edges x NT cols per 512-thr block (bf16) =============
// Round-4 structure (measured 135us edge1) with ONE change: in-loop barrier is
// lgkm-only (no vmcnt drain) so the t+1 gather prefetches genuinely stay in
// flight across the barrier instead of serializing a full L3/HBM round-trip
// per k-tile (the ~8K cycles/tile floor observed across rounds 2-11).
template<int K, int NT>
__global__ void __launch_bounds__(512, 4)
edge_gemm_pf(const short* __restrict__ AB, const short* __restrict__ BTf,
             const float* __restrict__ bias,
             const int* __restrict__ sSrc, const int* __restrict__ sDst,
             int* __restrict__ y) {
  constexpr int ROWS = 128;         // edges per block
  constexpr int KT = 64;            // k-tile
  constexpr int KTP = 72;           // LDS pitch (shorts): breaks bank alignment, keeps 16B
  constexpr int TILES = K / KT;
  constexpr int WCOLS = NT / 4;     // cols per wave (4 col-groups)
  constexpr int NTL = WCOLS / 16;
  __shared__ __align__(16) short hA[2][ROWS * KTP];  // 2 x 18432 B
  __shared__ int srcS[ROWS], dstS[ROWS];
  __shared__ int segDst[2][64];     // dst node per segment, per row-group
  __shared__ int segAtm[2][64];     // 1 = boundary dst (atomic), 0 = interior (store)
  __shared__ __align__(4) unsigned char rowSidC[ROWS]; // per-row segment id within group
  __shared__ int segD[2];

  const int tid = threadIdx.x;
  const int eBase = blockIdx.x * ROWS;
  const int wave = tid >> 6, lane = tid & 63, lm = lane & 15, q = lane >> 4;
  const int cg = wave & 3, rg = wave >> 2;
  const int cBase = cg * WCOLS;
  const int rg64 = rg * 64;

  if (tid < ROWS) { srcS[tid] = sSrc[eBase + tid]; dstS[tid] = sDst[eBase + tid]; }
  __syncthreads();

  // per-thread staging coords: 2 chunks (rows r0 and r0+64), fixed column chunk kc0
  const int r0 = tid >> 3, kc0 = (tid & 7) * 8;
  const int r1 = r0 + 64;
  const size_t dO0 = (size_t)dstS[r0] * (2 * K) + kc0;
  const size_t sO0 = (size_t)srcS[r0] * (2 * K) + K + kc0;
  const size_t dO1 = (size_t)dstS[r1] * (2 * K) + kc0;
  const size_t sO1 = (size_t)srcS[r1] * (2 * K) + K + kc0;

  // prologue: issue tile-0 gather prefetch FIRST (latency hidden under table build)
  uint4 av0 = *(const uint4*)(AB + dO0);
  uint4 bv0 = *(const uint4*)(AB + sO0);
  uint4 av1 = *(const uint4*)(AB + dO1);
  uint4 bv1 = *(const uint4*)(AB + sO1);

  // ---- waves 0,1: build per-row-group segment tables (consumed in epilogue;
  // visibility guaranteed by the main-loop barriers) ----
  if (tid < 2 * 64) {
    const int w = tid >> 6;          // row-group
    const int r = tid & 63;          // row within group
    const int row = tid;             // global row in block (group0: 0-63, group1: 64-127)
    int d = dstS[row];
    int prev = (r == 0) ? -1 : dstS[row - 1];
    bool flag = (r == 0) || (d != prev);
    unsigned long long mask = __ballot(flag);
    int Dtot = __popcll(mask);
    int sid = __popcll(mask & (0xFFFFFFFFFFFFFFFFull >> (63 - r))) - 1;
    rowSidC[row] = (unsigned char)sid;
    if (r == 0) segD[w] = Dtot;
    if (flag) {
      // neighbor dst just before this group / just after this group
      int prevOut = (w == 1) ? dstS[63]
                             : ((eBase > 0) ? sDst[eBase - 1] : -1);
      int nextOut = (w == 0) ? dstS[64]
                             : ((eBase + ROWS < NE) ? sDst[eBase + ROWS] : -1);
      bool atm = false;
      if (sid == 0 && prevOut == d) atm = true;
      if (sid == Dtot - 1 && nextOut == d) atm = true;
      segDst[w][sid] = d;
      segAtm[w][sid] = atm ? 1 : 0;
    }
  }

  f4v acc[4][NTL] = {};

  for (int t = 0; t < TILES; ++t) {
    // 1. issue s=0 bF loads (fly during convert + barrier)
    s8v bF0[NTL];
#pragma unroll
    for (int nt = 0; nt < NTL; ++nt)
      bF0[nt] = *(const s8v*)(BTf + (size_t)(t * 2) * (NT * 32) +
                              (cBase + nt * 16 + lm) * 32 + q * 8);
    // 2. convert prefetched gathers -> LDS (double-buffered)
    short* hbuf = hA[t & 1];
    {
      uint4 o;
      o.x = cvt_pair(av0.x, bv0.x); o.y = cvt_pair(av0.y, bv0.y);
      o.z = cvt_pair(av0.z, bv0.z); o.w = cvt_pair(av0.w, bv0.w);
      *(uint4*)(&hbuf[r0 * KTP + kc0]) = o;
      uint4 o1;
      o1.x = cvt_pair(av1.x, bv1.x); o1.y = cvt_pair(av1.y, bv1.y);
      o1.z = cvt_pair(av1.z, bv1.z); o1.w = cvt_pair(av1.w, bv1.w);
      *(uint4*)(&hbuf[r1 * KTP + kc0]) = o1;
    }
    // 3. prefetch next tile's gathers (STAY IN FLIGHT across the lgkm-only barrier)
    if (t + 1 < TILES) {
      const int kn = (t + 1) * KT;
      av0 = *(const uint4*)(AB + dO0 + kn);
      bv0 = *(const uint4*)(AB + sO0 + kn);
      av1 = *(const uint4*)(AB + dO1 + kn);
      bv1 = *(const uint4*)(AB + sO1 + kn);
    }
    barrier_lgkm_only();   // ds_writes visible; vmcnt NOT drained (the key change)
    // 4a. s=0 MFMA: aF per-mt from LDS, bF0 from regs
    {
      const int kl = q * 8;
      __builtin_amdgcn_s_setprio(1);
#pragma unroll
      for (int mt = 0; mt < 4; ++mt) {
        s8v aF = *(const s8v*)(&hbuf[(rg64 + mt * 16 + lm) * KTP + kl]);
#pragma unroll
        for (int nt = 0; nt < NTL; ++nt)
          acc[mt][nt] = __builtin_amdgcn_mfma_f32_16x16x32_bf16(aF, bF0[nt], acc[mt][nt], 0, 0, 0);
      }
      __builtin_amdgcn_s_setprio(0);
    }
    // 4b. s=1: load bF1 here (keeps bF register footprint at NTL)
    {
      s8v bF1[NTL];
#pragma unroll
      for (int nt = 0; nt < NTL; ++nt)
        bF1[nt] = *(const s8v*)(BTf + (size_t)(t * 2 + 1) * (NT * 32) +
                                (cBase + nt * 16 + lm) * 32 + q * 8);
      const int kl = 32 + q * 8;
      __builtin_amdgcn_s_setprio(1);
#pragma unroll
      for (int mt = 0; mt < 4; ++mt) {
        s8v aF = *(const s8v*)(&hbuf[(rg64 + mt * 16 + lm) * KTP + kl]);
#pragma unroll
        for (int nt = 0; nt < NTL; ++nt)
          acc[mt][nt] = __builtin_amdgcn_mfma_f32_16x16x32_bf16(aF, bF1[nt], acc[mt][nt], 0, 0, 0);
      }
      __builtin_amdgcn_s_setprio(0);
    }
  }

  // ---- epilogue: segmented max per column within this wave's row-group ----
  const int D = segD[rg];
  int sid[4][4];
#pragma unroll
  for (int mt = 0; mt < 4; ++mt) {
    unsigned pk = *(const unsigned*)(&rowSidC[rg64 + mt * 16 + q * 4]);  // 4B aligned
#pragma unroll
    for (int i = 0; i < 4; ++i) sid[mt][i] = (int)((pk >> (8 * i)) & 255u);
  }
#pragma unroll
  for (int nt = 0; nt < NTL; ++nt) {
    const int col = cBase + nt * 16 + lm;
    const float bvv = bias[col];
    for (int s = 0; s < D; ++s) {
      float m = -1e30f;
#pragma unroll
      for (int mt = 0; mt < 4; ++mt)
#pragma unroll
        for (int i = 0; i < 4; ++i)
          m = fmaxf(m, sid[mt][i] == s ? acc[mt][nt][i] : -1e30f);
      // reduce across the 4 q-lanes holding this column
      m = fmaxf(m, __shfl_xor(m, 16));
      m = fmaxf(m, __shfl_xor(m, 32));
      if (q == 0) {
        float v = m + bvv;
        int* addr = &y[(size_t)segDst[rg][s] * NT + col];
        if (segAtm[rg][s]) {
          if (v > 0.f) atomicMax(addr, __float_as_int(v));
        } else {
          *addr = __float_as_int(fmaxf(v, 0.f));   // group owns this dst: plain store
        }
      }
    }
  }
}

// ================= head: one wave per node =================
__global__ void __launch_bounds__(64)
head_kernel(const float* __restrict__ y2, const float* __restrict__ W3,
            const float* __restrict__ b3, const float* __restrict__ W4,
            const float* __restrict__ b4, float* __restrict__ out) {
  const int n = blockIdx.x, j = threadIdx.x;
  const float* yr = y2 + (size_t)n * 128;
  float acc = 0.f;
#pragma unroll
  for (int k = 0; k < 128; ++k) acc += yr[k] * W3[k * 64 + j];
  acc += b3[j];
  float h = acc > 0.f ? acc : 0.f;
  float p = h * W4[j];
#pragma unroll
  for (int off = 32; off; off >>= 1) p += __shfl_down(p, off);
  if (j == 0) {
    float z = p + b4[0];
    out[n] = 1.f / (1.f + expf(-z));
  }
}

__global__ void diag_kernel(float* out, float v) { out[0] = v; }

extern "C" void kernel_launch(void* const* d_in, const int* in_sizes, int n_in,
                              void* d_out, int out_size, void* d_ws, size_t ws_size,
                              hipStream_t stream) {
  const float* x   = (const float*)d_in[0];
  const int*   ei  = (const int*)d_in[1];
  const float* W1a = (const float*)d_in[2];
  const float* b1a = (const float*)d_in[3];
  const float* W2a = (const float*)d_in[4];
  const float* b2a = (const float*)d_in[5];
  const float* W1b = (const float*)d_in[6];
  const float* b1b = (const float*)d_in[7];
  const float* W2b = (const float*)d_in[8];
  const float* b2b = (const float*)d_in[9];
  const float* W3  = (const float*)d_in[10];
  const float* b3  = (const float*)d_in[11];
  const float* W4  = (const float*)d_in[12];
  const float* b4  = (const float*)d_in[13];

  // workspace layout (peak 34,211,968 B)
  char* ws = (char*)d_ws;
  short* Wp1T = (short*)(ws + 0);          //  262144 B [1024][128]
  short* Wp2T = (short*)(ws + 262144);     //  262144 B [512][256]
  short* BTf1 = (short*)(ws + 524288);     //  262144 B W2a^T fragment layout
  short* BTf2 = (short*)(ws + 786432);     //   65536 B W2b^T fragment layout
  short* A1B1 = (short*)(ws + 851968);     // 20480000 B [10000][1024] bf16
  short* A2B2 = (short*)(ws + 851968);     // reuse (A1B1 dead): [10000][512]
  int*   Y1   = (int*)(ws + 21331968);     // 10240000 B [10000][256] fp32
  int*   Y2   = (int*)(ws + 21331968);     // reuse (Y1 dead): [10000][128] fp32
  int*   cnt  = (int*)(ws + 31571968);     //    40000 B
  int*   cur  = (int*)(ws + 31611968);     //    40000 B
  int*   sSrc = (int*)(ws + 31651968);     //  1280000 B
  int*   sDst = (int*)(ws + 32931968);     //  1280000 B

  if (ws_size < 34211968) {                // diagnostic: encode ws_size in the absmax error
    diag_kernel<<<1, 1, 0, stream>>>((float*)d_out, (float)ws_size);
    return;
  }

  // ---- counting sort by dst ----
  hipMemsetAsync(cnt, 0, 40000, stream);
  hist_kernel<<<1250, 256, 0, stream>>>(ei, cnt);
  scan_kernel<<<1, 1024, 0, stream>>>(cnt, cur);
  scatter_kernel<<<1250, 256, 0, stream>>>(ei, cur, sSrc, sDst);

  prep_weights<<<1664, 256, 0, stream>>>(W1a, W1b, W2a, W2b, Wp1T, Wp2T, BTf1, BTf2);

  // EdgeConv 1
  node_gemm<128><<<dim3(157, 4), 256, 0, stream>>>(x, Wp1T, b1a, 512, A1B1, 1024);
  hipMemsetAsync(Y1, 0, (size_t)NN * 256 * 4, stream);
  edge_gemm_pf<512, 256><<<2500, 512, 0, stream>>>(A1B1, BTf1, b2a, sSrc, sDst, Y1);

  // EdgeConv 2 (A2B2 overwrites dead A1B1; Y2 memset AFTER node_gemm reads aliased Y1)
  node_gemm<256><<<dim3(157, 2), 256, 0, stream>>>((const float*)Y1, Wp2T, b1b, 256, A2B2, 512);
  hipMemsetAsync(Y2, 0, (size_t)NN * 128 * 4, stream);
  edge_gemm_pf<256, 128><<<2500, 512, 0, stream>>>(A2B2, BTf2, b2b, sSrc, sDst, Y2);

  // Head
  head_kernel<<<NN, 64, 0, stream>>>((const float*)Y2, W3, b3, W4, b4, (float*)d_out);
}

// Round 13
// 374.242 us; speedup vs baseline: 1.1684x; 1.0547x over previous
//
#include <hip/hip_runtime.h>
#include <math.h>

#define NN 10000
#define NE 320000

typedef __attribute__((ext_vector_type(8))) _Float16 h8v;    // 8 f16 (4 VGPRs) MFMA frag
typedef __attribute__((ext_vector_type(4))) float f4v;       // MFMA accumulator

__device__ __forceinline__ short f2h(float f) {
  _Float16 h = (_Float16)f;            // v_cvt_f16_f32 (RNE)
  short s; __builtin_memcpy(&s, &h, 2); return s;
}
// relu(f16a + f16b) on 8 packed f16 lanes: native clang vector arithmetic lowers
// to 4x v_pk_add_f16 + 4x v_pk_max_f16 with FULL register-allocator freedom
// (no asm operand pinning; compiled+ran clean in round 11).
__device__ __forceinline__ uint4 cvt8(uint4 ua, uint4 ub) {
  h8v a, b;
  __builtin_memcpy(&a, &ua, 16);
  __builtin_memcpy(&b, &ub, 16);
  h8v r = a + b;
  r = __builtin_elementwise_max(r, (h8v)(_Float16)0.0f);
  uint4 o; __builtin_memcpy(&o, &r, 16);
  return o;
}

// lgkm-only barrier (round 12: neutral vs __syncthreads, kept for the marginal
// freedom of leaving gather prefetches in flight across the barrier).
__device__ __forceinline__ void barrier_lgkm_only() {
  asm volatile("s_waitcnt lgkmcnt(0)" ::: "memory");
  __builtin_amdgcn_s_barrier();
}

// ================= edge sort by dst (counting sort) =================
__global__ void hist_kernel(const int* __restrict__ ei, int* __restrict__ cnt) {
  int e = blockIdx.x * 256 + threadIdx.x;
  if (e < NE) atomicAdd(&cnt[ei[NE + e]], 1);
}

__global__ void __launch_bounds__(1024)
scan_kernel(const int* __restrict__ cnt, int* __restrict__ cur) {
  __shared__ int part[1024];
  const int t = threadIdx.x;
  const int base = t * 10;
  int local[10];
  int s = 0;
#pragma unroll
  for (int u = 0; u < 10; ++u) {
    int c = (base + u < NN) ? cnt[base + u] : 0;
    local[u] = s; s += c;
  }
  part[t] = s;
  __syncthreads();
  for (int off = 1; off < 1024; off <<= 1) {
    int v = part[t];
    int w = (t >= off) ? part[t - off] : 0;
    __syncthreads();
    part[t] = v + w;
    __syncthreads();
  }
  int excl = (t == 0) ? 0 : part[t - 1];
#pragma unroll
  for (int u = 0; u < 10; ++u)
    if (base + u < NN) cur[base + u] = excl + local[u];
}

__global__ void scatter_kernel(const int* __restrict__ ei, int* __restrict__ cur,
                               int* __restrict__ sSrc, int* __restrict__ sDst) {
  int e = blockIdx.x * 256 + threadIdx.x;
  if (e < NE) {
    int d = ei[NE + e];
    int p = atomicAdd(&cur[d], 1);
    sSrc[p] = ei[e];
    sDst[p] = d;
  }
}

// ================= prep: combined/transposed weights, fp32 -> f16 =================
// Wp1T [1024][128], Wp2T [512][256] : node-GEMM layouts (row n, col k)
// BTf1 / BTf2 : edge-GEMM fragment layout: idx = (k>>5)*(NT*32) + n*32 + (k&31)
__global__ void prep_weights(const float* __restrict__ W1a, const float* __restrict__ W1b,
                             const float* __restrict__ W2a, const float* __restrict__ W2b,
                             short* __restrict__ Wp1T, short* __restrict__ Wp2T,
                             short* __restrict__ BTf1, short* __restrict__ BTf2) {
  int i = blockIdx.x * 256 + threadIdx.x;
  if (i < 131072) {                        // Wp1T[j][k], j<1024, k<128
    int j = i >> 7, k = i & 127;
    float v;
    if (j < 512) v = W1a[k * 512 + j] - W1a[(k + 128) * 512 + j];
    else         v = W1a[(k + 128) * 512 + (j - 512)];
    Wp1T[i] = f2h(v);
  } else if (i < 262144) {                 // Wp2T[j][k], j<512, k<256
    int t = i - 131072;
    int j = t >> 8, k = t & 255;
    float v;
    if (j < 256) v = W1b[k * 256 + j] - W1b[(k + 256) * 256 + j];
    else         v = W1b[(k + 256) * 256 + (j - 256)];
    Wp2T[t] = f2h(v);
  } else if (i < 393216) {                 // BTf1: W2a^T fragment layout (NT=256, K=512)
    int t = i - 262144;
    int n = t >> 9, k = t & 511;
    BTf1[(k >> 5) * 8192 + n * 32 + (k & 31)] = f2h(W2a[k * 256 + n]);
  } else if (i < 425984) {                 // BTf2: W2b^T fragment layout (NT=128, K=256)
    int t = i - 393216;
    int n = t >> 8, k = t & 255;
    BTf2[(k >> 5) * 4096 + n * 32 + (k & 31)] = f2h(W2b[k * 128 + n]);
  }
}

// ================= node GEMM: C[NN][Ntot](f16) = A[NN][K](fp32) @ BT^T + bias ===========
template<int K>
__global__ void __launch_bounds__(256)
node_gemm(const float* __restrict__ A, const short* __restrict__ BT,
          const float* __restrict__ bias, int biasLen,
          short* __restrict__ C, int Ntot) {
  const int rowBase = blockIdx.x * 64;
  const int wave = threadIdx.x >> 6, lane = threadIdx.x & 63;
  const int colBase = blockIdx.y * 256 + wave * 64;
  const int lm = lane & 15, q = lane >> 4;
  f4v acc[4][4] = {};
  int arow[4];
#pragma unroll
  for (int mt = 0; mt < 4; ++mt) {
    int r = rowBase + mt * 16 + lm;
    arow[mt] = r < NN ? r : NN - 1;        // clamp; stores guarded below
  }
  for (int kk = 0; kk < K; kk += 32) {
    const int k = kk + q * 8;
    h8v aF[4], bF[4];
#pragma unroll
    for (int mt = 0; mt < 4; ++mt) {
      const float4* ap = (const float4*)(A + (size_t)arow[mt] * K + k);
      float4 x0 = ap[0], x1 = ap[1];
      h8v t;
      t[0] = (_Float16)x0.x; t[1] = (_Float16)x0.y; t[2] = (_Float16)x0.z; t[3] = (_Float16)x0.w;
      t[4] = (_Float16)x1.x; t[5] = (_Float16)x1.y; t[6] = (_Float16)x1.z; t[7] = (_Float16)x1.w;
      aF[mt] = t;
    }
#pragma unroll
    for (int nt = 0; nt < 4; ++nt)
      bF[nt] = *(const h8v*)(BT + (size_t)(colBase + nt * 16 + lm) * K + k);
#pragma unroll
    for (int mt = 0; mt < 4; ++mt)
#pragma unroll
      for (int nt = 0; nt < 4; ++nt)
        acc[mt][nt] = __builtin_amdgcn_mfma_f32_16x16x32_f16(aF[mt], bF[nt], acc[mt][nt], 0, 0, 0);
  }
#pragma unroll
  for (int nt = 0; nt < 4; ++nt) {
    int col = colBase + nt * 16 + lm;
    float bv = (col < biasLen) ? bias[col] : 0.0f;
#pragma unroll
    for (int mt = 0; mt < 4; ++mt) {
#pragma unroll
      for (int i = 0; i < 4; ++i) {
        int row = rowBase + mt * 16 + q * 4 + i;   // C/D: col=lane&15, row=q*4+reg
        if (row < NN) C[(size_t)row * Ntot + col] = f2h(acc[mt][nt][i] + bv);
      }
    }
  }
}

// ================= edge GEMM: f16, 256-thread (4-wave) blocks at (256,3) ==============
// The f16 convert (proven -25us VALU busy, round 7) needs ~140 unified regs:
// (512,4)=128-reg budget spills acc to scratch (rounds 6/9/11: WRITE 130-343MB);
// (512,3) allows 170 but 8-wave blocks quantize to 1 block/CU (22% occ, round 7).
// 4-wave blocks at (256,3): 170-reg budget fits demand AND 3 blocks/CU = 12
// waves/CU (~37%) -- same occupancy as the bf16 baseline, no spill.
// Geometry: per-wave output 64x64. NCG=NT/64 col-groups, NRG=4/NCG row-groups
// of 64 rows; ROWS=64*NRG edges/block. edge1: 64-edge, 4 cg (5000 blocks);
// edge2: 128-edge, 2 cg x 2 rg (2500 blocks).
// Epilogue: per-row-group segment table; ONE memory op per (col, distinct dst):
// plain store for group-interior dsts, atomicMax for group/block-boundary dsts.
template<int K, int NT, int ROWS>
__global__ void __launch_bounds__(256, 3)
edge_gemm_pf(const short* __restrict__ AB, const short* __restrict__ BTf,
             const float* __restrict__ bias,
             const int* __restrict__ sSrc, const int* __restrict__ sDst,
             int* __restrict__ y) {
  constexpr int KT = 64;            // k-tile
  constexpr int KTP = 72;           // LDS pitch (shorts): breaks bank alignment, keeps 16B
  constexpr int TILES = K / KT;
  constexpr int NCG = NT / 64;      // col-groups (4 or 2)
  constexpr int NRG = 4 / NCG;      // row-groups (1 or 2)
  constexpr int CH = ROWS / 32;     // staged chunks per thread (2 or 4)
  constexpr int NTL = 4;            // 64 cols per wave
  static_assert(ROWS == 64 * NRG, "geometry");
  __shared__ __align__(16) short hA[2][ROWS * KTP];
  __shared__ int srcS[ROWS], dstS[ROWS];
  __shared__ int segDst[2][64];     // dst node per segment, per row-group
  __shared__ int segAtm[2][64];     // 1 = boundary dst (atomic), 0 = interior (store)
  __shared__ __align__(4) unsigned char rowSidC[ROWS]; // per-row segment id within group
  __shared__ int segD[2];

  const int tid = threadIdx.x;
  const int eBase = blockIdx.x * ROWS;
  const int wave = tid >> 6, lane = tid & 63, lm = lane & 15, q = lane >> 4;
  const int cg = wave % NCG, rg = wave / NCG;
  const int cBase = cg * 64;
  const int rg64 = rg * 64;

  if (tid < ROWS) { srcS[tid] = sSrc[eBase + tid]; dstS[tid] = sDst[eBase + tid]; }
  __syncthreads();

  // per-thread staging coords: CH chunks (rows r0+32c), fixed column chunk kc0
  const int r0 = tid >> 3, kc0 = (tid & 7) * 8;
  size_t dO[CH], sO[CH];
#pragma unroll
  for (int c = 0; c < CH; ++c) {
    dO[c] = (size_t)dstS[r0 + 32 * c] * (2 * K) + kc0;
    sO[c] = (size_t)srcS[r0 + 32 * c] * (2 * K) + K + kc0;
  }

  // prologue: issue tile-0 gather prefetch FIRST (latency hidden under table build)
  uint4 av[CH], bv[CH];
#pragma unroll
  for (int c = 0; c < CH; ++c) {
    av[c] = *(const uint4*)(AB + dO[c]);
    bv[c] = *(const uint4*)(AB + sO[c]);
  }

  // ---- waves 0..NRG-1: build per-row-group segment tables (consumed in epilogue;
  // visibility guaranteed by the main-loop barriers) ----
  if (tid < NRG * 64) {
    const int w = tid >> 6;          // row-group
    const int r = tid & 63;          // row within group
    const int row = tid;
    int d = dstS[row];
    int prev = (r == 0) ? -1 : dstS[row - 1];
    bool flag = (r == 0) || (d != prev);
    unsigned long long mask = __ballot(flag);
    int Dtot = __popcll(mask);
    int sid = __popcll(mask & (0xFFFFFFFFFFFFFFFFull >> (63 - r))) - 1;
    rowSidC[row] = (unsigned char)sid;
    if (r == 0) segD[w] = Dtot;
    if (flag) {
      int prevOut = (w > 0) ? dstS[w * 64 - 1]
                            : ((eBase > 0) ? sDst[eBase - 1] : -1);
      int nextOut = (w < NRG - 1) ? dstS[(w + 1) * 64]
                                  : ((eBase + ROWS < NE) ? sDst[eBase + ROWS] : -1);
      bool atm = false;
      if (sid == 0 && prevOut == d) atm = true;
      if (sid == Dtot - 1 && nextOut == d) atm = true;
      segDst[w][sid] = d;
      segAtm[w][sid] = atm ? 1 : 0;
    }
  }

  f4v acc[4][NTL] = {};

  for (int t = 0; t < TILES; ++t) {
    // 1. issue s=0 bF loads (fly during convert + barrier)
    h8v bF0[NTL];
#pragma unroll
    for (int nt = 0; nt < NTL; ++nt)
      bF0[nt] = *(const h8v*)(BTf + (size_t)(t * 2) * (NT * 32) +
                              (cBase + nt * 16 + lm) * 32 + q * 8);
    // 2. convert prefetched gathers -> LDS (double-buffered); packed-f16 ops
    short* hbuf = hA[t & 1];
#pragma unroll
    for (int c = 0; c < CH; ++c)
      *(uint4*)(&hbuf[(r0 + 32 * c) * KTP + kc0]) = cvt8(av[c], bv[c]);
    // 3. prefetch next tile's gathers (stay in flight across the lgkm-only barrier)
    if (t + 1 < TILES) {
      const int kn = (t + 1) * KT;
#pragma unroll
      for (int c = 0; c < CH; ++c) {
        av[c] = *(const uint4*)(AB + dO[c] + kn);
        bv[c] = *(const uint4*)(AB + sO[c] + kn);
      }
    }
    barrier_lgkm_only();
    // 4a. s=0 MFMA: aF per-mt from LDS, bF0 from regs
    {
      const int kl = q * 8;
      __builtin_amdgcn_s_setprio(1);
#pragma unroll
      for (int mt = 0; mt < 4; ++mt) {
        h8v aF = *(const h8v*)(&hbuf[(rg64 + mt * 16 + lm) * KTP + kl]);
#pragma unroll
        for (int nt = 0; nt < NTL; ++nt)
          acc[mt][nt] = __builtin_amdgcn_mfma_f32_16x16x32_f16(aF, bF0[nt], acc[mt][nt], 0, 0, 0);
      }
      __builtin_amdgcn_s_setprio(0);
    }
    // 4b. s=1: load bF1 here (keeps bF register footprint at NTL)
    {
      h8v bF1[NTL];
#pragma unroll
      for (int nt = 0; nt < NTL; ++nt)
        bF1[nt] = *(const h8v*)(BTf + (size_t)(t * 2 + 1) * (NT * 32) +
                                (cBase + nt * 16 + lm) * 32 + q * 8);
      const int kl = 32 + q * 8;
      __builtin_amdgcn_s_setprio(1);
#pragma unroll
      for (int mt = 0; mt < 4; ++mt) {
        h8v aF = *(const h8v*)(&hbuf[(rg64 + mt * 16 + lm) * KTP + kl]);
#pragma unroll
        for (int nt = 0; nt < NTL; ++nt)
          acc[mt][nt] = __builtin_amdgcn_mfma_f32_16x16x32_f16(aF, bF1[nt], acc[mt][nt], 0, 0, 0);
      }
      __builtin_amdgcn_s_setprio(0);
    }
  }

  // ---- epilogue: segmented max per column within this wave's row-group ----
  const int D = segD[rg];
  int sid[4][4];
#pragma unroll
  for (int mt = 0; mt < 4; ++mt) {
    unsigned pk = *(const unsigned*)(&rowSidC[rg64 + mt * 16 + q * 4]);  // 4B aligned
#pragma unroll
    for (int i = 0; i < 4; ++i) sid[mt][i] = (int)((pk >> (8 * i)) & 255u);
  }
#pragma unroll
  for (int nt = 0; nt < NTL; ++nt) {
    const int col = cBase + nt * 16 + lm;
    const float bvv = bias[col];
    for (int s = 0; s < D; ++s) {
      float m = -1e30f;
#pragma unroll
      for (int mt = 0; mt < 4; ++mt)
#pragma unroll
        for (int i = 0; i < 4; ++i)
          m = fmaxf(m, sid[mt][i] == s ? acc[mt][nt][i] : -1e30f);
      // reduce across the 4 q-lanes holding this column
      m = fmaxf(m, __shfl_xor(m, 16));
      m = fmaxf(m, __shfl_xor(m, 32));
      if (q == 0) {
        float v = m + bvv;
        int* addr = &y[(size_t)segDst[rg][s] * NT + col];
        if (segAtm[rg][s]) {
          if (v > 0.f) atomicMax(addr, __float_as_int(v));
        } else {
          *addr = __float_as_int(fmaxf(v, 0.f));   // group owns this dst: plain store
        }
      }
    }
  }
}

// ================= head: one wave per node =================
__global__ void __launch_bounds__(64)
head_kernel(const float* __restrict__ y2, const float* __restrict__ W3,
            const float* __restrict__ b3, const float* __restrict__ W4,
            const float* __restrict__ b4, float* __restrict__ out) {
  const int n = blockIdx.x, j = threadIdx.x;
  const float* yr = y2 + (size_t)n * 128;
  float acc = 0.f;
#pragma unroll
  for (int k = 0; k < 128; ++k) acc += yr[k] * W3[k * 64 + j];
  acc += b3[j];
  float h = acc > 0.f ? acc : 0.f;
  float p = h * W4[j];
#pragma unroll
  for (int off = 32; off; off >>= 1) p += __shfl_down(p, off);
  if (j == 0) {
    float z = p + b4[0];
    out[n] = 1.f / (1.f + expf(-z));
  }
}

__global__ void diag_kernel(float* out, float v) { out[0] = v; }

extern "C" void kernel_launch(void* const* d_in, const int* in_sizes, int n_in,
                              void* d_out, int out_size, void* d_ws, size_t ws_size,
                              hipStream_t stream) {
  const float* x   = (const float*)d_in[0];
  const int*   ei  = (const int*)d_in[1];
  const float* W1a = (const float*)d_in[2];
  const float* b1a = (const float*)d_in[3];
  const float* W2a = (const float*)d_in[4];
  const float* b2a = (const float*)d_in[5];
  const float* W1b = (const float*)d_in[6];
  const float* b1b = (const float*)d_in[7];
  const float* W2b = (const float*)d_in[8];
  const float* b2b = (const float*)d_in[9];
  const float* W3  = (const float*)d_in[10];
  const float* b3  = (const float*)d_in[11];
  const float* W4  = (const float*)d_in[12];
  const float* b4  = (const float*)d_in[13];

  // workspace layout (peak 34,211,968 B)
  char* ws = (char*)d_ws;
  short* Wp1T = (short*)(ws + 0);          //  262144 B [1024][128]
  short* Wp2T = (short*)(ws + 262144);     //  262144 B [512][256]
  short* BTf1 = (short*)(ws + 524288);     //  262144 B W2a^T fragment layout
  short* BTf2 = (short*)(ws + 786432);     //   65536 B W2b^T fragment layout
  short* A1B1 = (short*)(ws + 851968);     // 20480000 B [10000][1024] f16
  short* A2B2 = (short*)(ws + 851968);     // reuse (A1B1 dead): [10000][512]
  int*   Y1   = (int*)(ws + 21331968);     // 10240000 B [10000][256] fp32
  int*   Y2   = (int*)(ws + 21331968);     // reuse (Y1 dead): [10000][128] fp32
  int*   cnt  = (int*)(ws + 31571968);     //    40000 B
  int*   cur  = (int*)(ws + 31611968);     //    40000 B
  int*   sSrc = (int*)(ws + 31651968);     //  1280000 B
  int*   sDst = (int*)(ws + 32931968);     //  1280000 B

  if (ws_size < 34211968) {                // diagnostic: encode ws_size in the absmax error
    diag_kernel<<<1, 1, 0, stream>>>((float*)d_out, (float)ws_size);
    return;
  }

  // ---- counting sort by dst ----
  hipMemsetAsync(cnt, 0, 40000, stream);
  hist_kernel<<<1250, 256, 0, stream>>>(ei, cnt);
  scan_kernel<<<1, 1024, 0, stream>>>(cnt, cur);
  scatter_kernel<<<1250, 256, 0, stream>>>(ei, cur, sSrc, sDst);

  prep_weights<<<1664, 256, 0, stream>>>(W1a, W1b, W2a, W2b, Wp1T, Wp2T, BTf1, BTf2);

  // EdgeConv 1
  node_gemm<128><<<dim3(157, 4), 256, 0, stream>>>(x, Wp1T, b1a, 512, A1B1, 1024);
  hipMemsetAsync(Y1, 0, (size_t)NN * 256 * 4, stream);
  edge_gemm_pf<512, 256, 64><<<5000, 256, 0, stream>>>(A1B1, BTf1, b2a, sSrc, sDst, Y1);

  // EdgeConv 2 (A2B2 overwrites dead A1B1; Y2 memset AFTER node_gemm reads aliased Y1)
  node_gemm<256><<<dim3(157, 2), 256, 0, stream>>>((const float*)Y1, Wp2T, b1b, 256, A2B2, 512);
  hipMemsetAsync(Y2, 0, (size_t)NN * 128 * 4, stream);
  edge_gemm_pf<256, 128, 128><<<2500, 256, 0, stream>>>(A2B2, BTf2, b2b, sSrc, sDst, Y2);

  // Head
  head_kernel<<<NN, 64, 0, stream>>>((const float*)Y2, W3, b3, W4, b4, (float*)d_out);
}